// Round 1
// baseline (3313.041 us; speedup 1.0000x reference)
//
#include <hip/hip_runtime.h>

#define DD 64   // embedding dim, fixed by the problem

// ---------------- SpMM: out[rows[e], :] += vals[e] * x[cols[e], :] ----------------
// One thread per (edge, 4-float chunk): 16 lanes cover an edge's 64-float row.
__global__ __launch_bounds__(256) void spmm_scatter(
    const int* __restrict__ rows, const int* __restrict__ cols,
    const float* __restrict__ vals, const float* __restrict__ x,
    float* __restrict__ out, int nnz)
{
    int t = blockIdx.x * blockDim.x + threadIdx.x;
    int total = nnz * 16;
    if (t >= total) return;
    int e = t >> 4;
    int c = t & 15;
    int r   = rows[e];
    int col = cols[e];
    float v = vals[e];
    const float4 xv = *reinterpret_cast<const float4*>(x + (size_t)col * DD + (c << 2));
    float* o = out + (size_t)r * DD + (c << 2);
    unsafeAtomicAdd(o + 0, v * xv.x);
    unsafeAtomicAdd(o + 1, v * xv.y);
    unsafeAtomicAdd(o + 2, v * xv.z);
    unsafeAtomicAdd(o + 3, v * xv.w);
}

// ------------- Fused concat GEMM: out[r,:] = [a[r,:], b[r,:]] @ W (W: [128,64]) -------------
// Block = 256 threads = 4 rows x 64 cols. W staged in LDS (32 KB).
__global__ __launch_bounds__(256) void gemm_concat(
    const float* __restrict__ a,   // new_u  [nrows, 64]
    const float* __restrict__ b,   // u      [nrows, 64]
    const float* __restrict__ w,   // layer weight [128, 64], row-major
    float* __restrict__ out, int nrows)
{
    __shared__ float wl[128 * 64];
    // 8192 floats = 2048 float4 loaded by 256 threads (8 each)
    for (int i = threadIdx.x; i < 128 * 16; i += 256) {
        reinterpret_cast<float4*>(wl)[i] = reinterpret_cast<const float4*>(w)[i];
    }
    __syncthreads();

    int row = blockIdx.x * 4 + (threadIdx.x >> 6);
    int col = threadIdx.x & 63;
    if (row >= nrows) return;

    const float4* arow = reinterpret_cast<const float4*>(a + (size_t)row * DD);
    const float4* brow = reinterpret_cast<const float4*>(b + (size_t)row * DD);

    float acc = 0.f;
    #pragma unroll
    for (int j4 = 0; j4 < 16; ++j4) {
        float4 av = arow[j4];
        acc += av.x * wl[(j4 * 4 + 0) * 64 + col];
        acc += av.y * wl[(j4 * 4 + 1) * 64 + col];
        acc += av.z * wl[(j4 * 4 + 2) * 64 + col];
        acc += av.w * wl[(j4 * 4 + 3) * 64 + col];
    }
    #pragma unroll
    for (int j4 = 0; j4 < 16; ++j4) {
        float4 bv = brow[j4];
        acc += bv.x * wl[(64 + j4 * 4 + 0) * 64 + col];
        acc += bv.y * wl[(64 + j4 * 4 + 1) * 64 + col];
        acc += bv.z * wl[(64 + j4 * 4 + 2) * 64 + col];
        acc += bv.w * wl[(64 + j4 * 4 + 3) * 64 + col];
    }
    out[(size_t)row * DD + col] = acc;
}

extern "C" void kernel_launch(void* const* d_in, const int* in_sizes, int n_in,
                              void* d_out, int out_size, void* d_ws, size_t ws_size,
                              hipStream_t stream)
{
    const float* user_emb    = (const float*)d_in[0];
    const float* item_emb    = (const float*)d_in[1];
    const float* weights     = (const float*)d_in[2];
    const float* social_vals = (const float*)d_in[3];
    const float* inter_vals  = (const float*)d_in[4];
    const int*   social_rows = (const int*)d_in[5];
    const int*   social_cols = (const int*)d_in[6];
    const int*   inter_rows  = (const int*)d_in[7];
    const int*   inter_cols  = (const int*)d_in[8];

    const int D  = DD;
    const int U  = in_sizes[0] / D;
    const int I  = in_sizes[1] / D;
    const int L  = in_sizes[2] / (2 * D * D);
    const int ES = in_sizes[3];
    const int EI = in_sizes[4];

    float* out      = (float*)d_out;           // final_u [U, D]
    float* out_item = out + (size_t)U * D;     // item_emb passthrough [I, D]

    // workspace: tmp (spmm result) + ping-pong u buffers
    float* tmp = (float*)d_ws;
    float* u1  = tmp + (size_t)U * D;
    float* u2  = u1  + (size_t)U * D;          // only touched if L > 2
    float* ping[2] = { u1, u2 };
    int pi = 0;

    const size_t udbytes = (size_t)U * D * sizeof(float);
    const float* uprev = user_emb;

    for (int k = 0; k < L; ++k) {
        hipMemsetAsync(tmp, 0, udbytes, stream);
        int totalS = ES * 16;
        spmm_scatter<<<(totalS + 255) / 256, 256, 0, stream>>>(
            social_rows, social_cols, social_vals, uprev, tmp, ES);
        float* unext = (k == L - 1) ? out : ping[pi];
        gemm_concat<<<(U + 3) / 4, 256, 0, stream>>>(
            tmp, uprev, weights + (size_t)k * 2 * D * D, unext, U);
        uprev = unext;
        pi ^= 1;
    }

    // final_u += A_inter @ item_emb  (accumulate straight into d_out)
    int totalI = EI * 16;
    spmm_scatter<<<(totalI + 255) / 256, 256, 0, stream>>>(
        inter_rows, inter_cols, inter_vals, item_emb, out, EI);

    // output 1: item_emb passthrough
    hipMemcpyAsync(out_item, item_emb, (size_t)I * D * sizeof(float),
                   hipMemcpyDeviceToDevice, stream);
}

// Round 2
// 738.604 us; speedup vs baseline: 4.4855x; 4.4855x over previous
//
#include <hip/hip_runtime.h>

#define DD 64   // embedding dim, fixed by the problem

static inline size_t align16(size_t x) { return (x + 15) & ~(size_t)15; }

// ---------------- CSR build ----------------

__global__ __launch_bounds__(256) void hist_kernel(
    const int* __restrict__ rows, int* __restrict__ counts, int nnz)
{
    int e = blockIdx.x * 256 + threadIdx.x;
    if (e < nnz) atomicAdd(&counts[rows[e]], 1);
}

// Block scans 2048 elements (256 threads x 8). Exclusive scan out, block sum to bsums.
__global__ __launch_bounds__(256) void scan_partial(
    const int* __restrict__ in, int* __restrict__ out, int* __restrict__ bsums, int n)
{
    __shared__ int sh[256];
    int base = blockIdx.x * 2048 + threadIdx.x * 8;
    int v[8];
    int tsum = 0;
    #pragma unroll
    for (int j = 0; j < 8; ++j) {
        int idx = base + j;
        int x = (idx < n) ? in[idx] : 0;
        v[j] = tsum;          // thread-local exclusive prefix
        tsum += x;
    }
    sh[threadIdx.x] = tsum;
    __syncthreads();
    // Hillis-Steele inclusive scan over the 256 per-thread sums
    for (int off = 1; off < 256; off <<= 1) {
        int t = (threadIdx.x >= off) ? sh[threadIdx.x - off] : 0;
        __syncthreads();
        sh[threadIdx.x] += t;
        __syncthreads();
    }
    int texc = sh[threadIdx.x] - tsum;
    #pragma unroll
    for (int j = 0; j < 8; ++j) {
        int idx = base + j;
        if (idx < n) out[idx] = texc + v[j];
    }
    if (threadIdx.x == 255) bsums[blockIdx.x] = sh[255];
}

// Single-thread exclusive scan of block sums (nb ~ 49); also writes row_ptr[n] = total.
__global__ void scan_top(int* bsums, int nb, int* row_ptr, int n)
{
    int run = 0;
    for (int i = 0; i < nb; ++i) { int t = bsums[i]; bsums[i] = run; run += t; }
    row_ptr[n] = run;
}

__global__ __launch_bounds__(256) void scan_add(
    int* __restrict__ out, const int* __restrict__ bsums, int n)
{
    int i = blockIdx.x * 256 + threadIdx.x;
    if (i < n) out[i] += bsums[i >> 11];
}

__global__ __launch_bounds__(256) void scatter_edges(
    const int* __restrict__ rows, const int* __restrict__ cols,
    const float* __restrict__ vals, int* __restrict__ cursor,
    int* __restrict__ ecol, float* __restrict__ eval, int nnz)
{
    int e = blockIdx.x * 256 + threadIdx.x;
    if (e >= nnz) return;
    int slot = atomicAdd(&cursor[rows[e]], 1);
    ecol[slot] = cols[e];
    eval[slot] = vals[e];
}

// ---------------- SpMM (CSR row-gather) ----------------
// 16 lanes per destination row; each lane owns 4 of the 64 columns.
template <bool ADD>
__global__ __launch_bounds__(256) void spmm_csr(
    const int* __restrict__ row_ptr, const int* __restrict__ ecol,
    const float* __restrict__ eval, const float* __restrict__ x,
    float* __restrict__ out, int nrows)
{
    int g    = (blockIdx.x * 256 + threadIdx.x) >> 4;   // dest row
    int lane = threadIdx.x & 15;
    if (g >= nrows) return;
    int s = row_ptr[g], e = row_ptr[g + 1];
    float4 acc = make_float4(0.f, 0.f, 0.f, 0.f);
    for (int i = s; i < e; ++i) {
        int   c = ecol[i];
        float v = eval[i];
        float4 xv = *reinterpret_cast<const float4*>(x + (size_t)c * DD + lane * 4);
        acc.x += v * xv.x; acc.y += v * xv.y; acc.z += v * xv.z; acc.w += v * xv.w;
    }
    float* o = out + (size_t)g * DD + lane * 4;
    if (ADD) {
        float4 cur = *reinterpret_cast<const float4*>(o);
        acc.x += cur.x; acc.y += cur.y; acc.z += cur.z; acc.w += cur.w;
    }
    *reinterpret_cast<float4*>(o) = acc;
}

// ------------- Fused concat GEMM: out[r,:] = [a[r,:], b[r,:]] @ W (W: [128,64]) -------------
__global__ __launch_bounds__(256) void gemm_concat(
    const float* __restrict__ a,   // new_u  [nrows, 64]
    const float* __restrict__ b,   // u      [nrows, 64]
    const float* __restrict__ w,   // layer weight [128, 64], row-major
    float* __restrict__ out, int nrows)
{
    __shared__ float wl[128 * 64];
    for (int i = threadIdx.x; i < 128 * 16; i += 256) {
        reinterpret_cast<float4*>(wl)[i] = reinterpret_cast<const float4*>(w)[i];
    }
    __syncthreads();

    int row = blockIdx.x * 4 + (threadIdx.x >> 6);
    int col = threadIdx.x & 63;
    if (row >= nrows) return;

    const float4* arow = reinterpret_cast<const float4*>(a + (size_t)row * DD);
    const float4* brow = reinterpret_cast<const float4*>(b + (size_t)row * DD);

    float acc = 0.f;
    #pragma unroll
    for (int j4 = 0; j4 < 16; ++j4) {
        float4 av = arow[j4];
        acc += av.x * wl[(j4 * 4 + 0) * 64 + col];
        acc += av.y * wl[(j4 * 4 + 1) * 64 + col];
        acc += av.z * wl[(j4 * 4 + 2) * 64 + col];
        acc += av.w * wl[(j4 * 4 + 3) * 64 + col];
    }
    #pragma unroll
    for (int j4 = 0; j4 < 16; ++j4) {
        float4 bv = brow[j4];
        acc += bv.x * wl[(64 + j4 * 4 + 0) * 64 + col];
        acc += bv.y * wl[(64 + j4 * 4 + 1) * 64 + col];
        acc += bv.z * wl[(64 + j4 * 4 + 2) * 64 + col];
        acc += bv.w * wl[(64 + j4 * 4 + 3) * 64 + col];
    }
    out[(size_t)row * DD + col] = acc;
}

// ---------------- host-side CSR build helper ----------------
static void build_csr(const int* rows, const int* cols, const float* vals, int nnz,
                      int nrows, int* row_ptr, int* cursor, int* bsums,
                      int* ecol, float* eval, hipStream_t stream)
{
    int nb = (nrows + 2047) / 2048;
    hipMemsetAsync(cursor, 0, (size_t)nrows * sizeof(int), stream);
    hist_kernel<<<(nnz + 255) / 256, 256, 0, stream>>>(rows, cursor, nnz);
    scan_partial<<<nb, 256, 0, stream>>>(cursor, row_ptr, bsums, nrows);
    scan_top<<<1, 1, 0, stream>>>(bsums, nb, row_ptr, nrows);
    scan_add<<<(nrows + 255) / 256, 256, 0, stream>>>(row_ptr, bsums, nrows);
    hipMemcpyAsync(cursor, row_ptr, (size_t)nrows * sizeof(int),
                   hipMemcpyDeviceToDevice, stream);
    scatter_edges<<<(nnz + 255) / 256, 256, 0, stream>>>(
        rows, cols, vals, cursor, ecol, eval, nnz);
}

extern "C" void kernel_launch(void* const* d_in, const int* in_sizes, int n_in,
                              void* d_out, int out_size, void* d_ws, size_t ws_size,
                              hipStream_t stream)
{
    const float* user_emb    = (const float*)d_in[0];
    const float* item_emb    = (const float*)d_in[1];
    const float* weights     = (const float*)d_in[2];
    const float* social_vals = (const float*)d_in[3];
    const float* inter_vals  = (const float*)d_in[4];
    const int*   social_rows = (const int*)d_in[5];
    const int*   social_cols = (const int*)d_in[6];
    const int*   inter_rows  = (const int*)d_in[7];
    const int*   inter_cols  = (const int*)d_in[8];

    const int D  = DD;
    const int U  = in_sizes[0] / D;
    const int I  = in_sizes[1] / D;
    const int L  = in_sizes[2] / (2 * D * D);
    const int ES = in_sizes[3];
    const int EI = in_sizes[4];

    float* out      = (float*)d_out;           // final_u [U, D]
    float* out_item = out + (size_t)U * D;     // item_emb passthrough [I, D]

    // ---- workspace layout (all 16B aligned) ----
    char* p = (char*)d_ws;
    size_t off = 0;
    auto take = [&](size_t bytes) { char* r = p + off; off += align16(bytes); return r; };

    int*   srow_ptr = (int*)take((size_t)(U + 1) * sizeof(int));
    int*   irow_ptr = (int*)take((size_t)(U + 1) * sizeof(int));
    int*   cursor   = (int*)take((size_t)(U + 1) * sizeof(int));
    int*   bsums    = (int*)take(1024 * sizeof(int));
    int*   s_ecol   = (int*)take((size_t)ES * sizeof(int));
    float* s_eval   = (float*)take((size_t)ES * sizeof(float));
    int*   i_ecol   = (int*)take((size_t)EI * sizeof(int));
    float* i_eval   = (float*)take((size_t)EI * sizeof(float));
    float* tmpA     = (float*)take((size_t)U * D * sizeof(float));
    float* uB       = (float*)take((size_t)U * D * sizeof(float));
    float* uC       = (float*)take((size_t)U * D * sizeof(float)); // touched only if L > 2

    // ---- build both CSRs (graphs are static per call) ----
    build_csr(social_rows, social_cols, social_vals, ES, U,
              srow_ptr, cursor, bsums, s_ecol, s_eval, stream);
    build_csr(inter_rows, inter_cols, inter_vals, EI, U,
              irow_ptr, cursor, bsums, i_ecol, i_eval, stream);

    // ---- layers ----
    const float* uprev = user_emb;
    int which = 0;
    int spmm_blocks = ((U * 16) + 255) / 256;
    for (int k = 0; k < L; ++k) {
        spmm_csr<false><<<spmm_blocks, 256, 0, stream>>>(
            srow_ptr, s_ecol, s_eval, uprev, tmpA, U);
        float* unext = (k == L - 1) ? out : (which ? uC : uB);
        gemm_concat<<<(U + 3) / 4, 256, 0, stream>>>(
            tmpA, uprev, weights + (size_t)k * 2 * D * D, unext, U);
        uprev = unext;
        which ^= 1;
    }

    // final_u += A_inter @ item_emb  (accumulate into d_out)
    spmm_csr<true><<<spmm_blocks, 256, 0, stream>>>(
        irow_ptr, i_ecol, i_eval, item_emb, out, U);

    // output 1: item_emb passthrough
    hipMemcpyAsync(out_item, item_emb, (size_t)I * D * sizeof(float),
                   hipMemcpyDeviceToDevice, stream);
}